// Round 12
// baseline (254.496 us; speedup 1.0000x reference)
//
#include <hip/hip_runtime.h>
#include <hip/hip_fp16.h>

// Problem constants
#define B_ 64
#define SW_ 132                 // stored k2 rows: [0,128] real + [129,131] zero pad
#define SIMG_ (256 * SW_)       // 33792 packed half2 per channel plane
#define TIMG_ (3 * SIMG_)       // per batch item per tensor
#define TELEMS_ ((size_t)B_ * TIMG_)
#define SST_ 257                // S row stride (odd -> conflict-free strided access)

typedef unsigned u32;

// ---- packed half2 primitives (compile to v_pk_*_f16 / v_alignbit) --------
__device__ __forceinline__ u32 h2add(u32 a, u32 b) {
  __half2 r = __hadd2(__builtin_bit_cast(__half2, a), __builtin_bit_cast(__half2, b));
  return __builtin_bit_cast(u32, r);
}
__device__ __forceinline__ u32 h2sub(u32 a, u32 b) {
  __half2 r = __hsub2(__builtin_bit_cast(__half2, a), __builtin_bit_cast(__half2, b));
  return __builtin_bit_cast(u32, r);
}
__device__ __forceinline__ u32 h2mul(u32 a, u32 b) {
  __half2 r = __hmul2(__builtin_bit_cast(__half2, a), __builtin_bit_cast(__half2, b));
  return __builtin_bit_cast(u32, r);
}
__device__ __forceinline__ u32 h2fma(u32 a, u32 b, u32 c) {
  __half2 r = __hfma2(__builtin_bit_cast(__half2, a), __builtin_bit_cast(__half2, b),
                      __builtin_bit_cast(__half2, c));
  return __builtin_bit_cast(u32, r);
}
__device__ __forceinline__ u32 rot16(u32 u) { return (u >> 16) | (u << 16); }
#define NEG_HI_ 0x80000000u     // flip sign of .y (im)
#define NEG_LO_ 0x00008000u     // flip sign of .x (re)
#define HALF2C_ 0x38003800u     // {0.5h, 0.5h}

// complex mul by twiddle given duplicated halves tr={c,c}, ti={s,s}:
// {x.re*c - x.im*s, x.im*c + x.re*s}
__device__ __forceinline__ u32 cmulh(u32 x, u32 tr, u32 ti) {
  u32 m = h2mul(rot16(x), ti);          // {x.im*s, x.re*s}
  return h2fma(x, tr, m ^ NEG_LO_);     // {x.re*c - x.im*s, x.im*c + x.re*s}
}

__device__ __forceinline__ u32 f2u(float2 v) {
  __half2 h = __float22half2_rn(v);
  return __builtin_bit_cast(u32, h);
}
__device__ __forceinline__ float2 u2f(u32 u) {
  return __half22float2(__builtin_bit_cast(__half2, u));
}
__device__ __forceinline__ float2 cmulf(float2 a, float2 b) {
  return make_float2(a.x * b.x - a.y * b.y, a.x * b.y + a.y * b.x);
}

// radix-4 DIF butterfly on 4 half2 slots (intra-lane), optional twiddles
__device__ __forceinline__ void bfly4h(u32 x[4], const u32* twr, const u32* twi, bool tw) {
  u32 a = h2add(x[0], x[2]);
  u32 b = h2sub(x[0], x[2]);
  u32 c = h2add(x[1], x[3]);
  u32 d = h2sub(x[1], x[3]);
  u32 e = rot16(d);                     // {d.y, d.x}
  u32 y1 = h2add(b, e ^ NEG_HI_);       // b - i d = {b.x + d.y, b.y - d.x}
  u32 y2 = h2sub(a, c);
  u32 y3 = h2add(b, e ^ NEG_LO_);       // b + i d = {b.x - d.y, b.y + d.x}
  x[0] = h2add(a, c);
  if (tw) { y1 = cmulh(y1, twr[0], twi[0]); y2 = cmulh(y2, twr[1], twi[1]);
            y3 = cmulh(y3, twr[2], twi[2]); }
  x[1] = y1; x[2] = y2; x[3] = y3;
}

// ---- gfx950-native lane exchanges ----------------------------------------
__device__ __forceinline__ void swap16(u32& A, u32& B) {
  asm("v_permlane16_swap_b32 %0, %1" : "+v"(A), "+v"(B));
}
__device__ __forceinline__ void swap32(u32& A, u32& B) {
  asm("v_permlane32_swap_b32 %0, %1" : "+v"(A), "+v"(B));
}
template <int BIT>
__device__ __forceinline__ void xsel(u32& A, u32& B, int r) {
  bool hi = (r >> BIT) & 1;
  int send = hi ? (int)A : (int)B;
  int got;
  if constexpr (BIT == 0)
    got = __builtin_amdgcn_update_dpp(0, send, 0xB1, 0xF, 0xF, false);
  else if constexpr (BIT == 1)
    got = __builtin_amdgcn_update_dpp(0, send, 0x4E, 0xF, 0xF, false);
  else if constexpr (BIT == 2)
    got = __builtin_amdgcn_ds_swizzle(send, 0x101F);
  else
    got = __builtin_amdgcn_ds_swizzle(send, 0x201F);
  if (hi) A = (u32)got; else B = (u32)got;
}
__device__ __forceinline__ void xdig45(u32 u[4]) {
  swap16(u[0], u[1]);
  swap16(u[2], u[3]);
  swap32(u[0], u[2]);
  swap32(u[1], u[3]);
}
template <int BIT>
__device__ __forceinline__ void xdig(u32 u[4], int r) {
  xsel<BIT>(u[0], u[1], r);
  xsel<BIT>(u[2], u[3], r);
  xsel<BIT + 1>(u[0], u[2], r);
  xsel<BIT + 1>(u[1], u[3], r);
}

// NF independent 256-pt radix-4 DIF FFTs per wave, fully half2-resident.
// Input u[f][4] half2 with slot = d3 (element e = r + 64*slot). Output packed:
// lane r slot s holds X[k], k = 64*s + 16*(r&3) + 4*((r>>2)&3) + (r>>4).
template <int NF>
__device__ __forceinline__ void fft256h(u32 (&u)[NF][4], int r,
                                        const u32 twr[9], const u32 twi[9]) {
#pragma unroll
  for (int f = 0; f < NF; ++f) bfly4h(u[f], twr + 0, twi + 0, true);
#pragma unroll
  for (int f = 0; f < NF; ++f) xdig45(u[f]);                    // d3 <-> d2
#pragma unroll
  for (int f = 0; f < NF; ++f) bfly4h(u[f], twr + 3, twi + 3, true);
#pragma unroll
  for (int f = 0; f < NF; ++f) xdig<2>(u[f], r);                // d2 <-> d1
#pragma unroll
  for (int f = 0; f < NF; ++f) bfly4h(u[f], twr + 6, twi + 6, true);
#pragma unroll
  for (int f = 0; f < NF; ++f) xdig<0>(u[f], r);                // d1 <-> d0
#pragma unroll
  for (int f = 0; f < NF; ++f) bfly4h(u[f], twr, twi, false);
}

// per-lane duplicated-half2 twiddles (function of lane id only)
__device__ __forceinline__ void tw_init_h(u32 twr[9], u32 twi[9], int r) {
  float2 t[9];
  float s, c;
  __sincosf(-6.283185307179586f * (float)r / 256.0f, &s, &c);
  t[0] = make_float2(c, s); t[1] = cmulf(t[0], t[0]); t[2] = cmulf(t[1], t[0]);
  __sincosf(-6.283185307179586f * (float)(r & 15) / 64.0f, &s, &c);
  t[3] = make_float2(c, s); t[4] = cmulf(t[3], t[3]); t[5] = cmulf(t[4], t[3]);
  __sincosf(-6.283185307179586f * (float)(r & 3) / 16.0f, &s, &c);
  t[6] = make_float2(c, s); t[7] = cmulf(t[6], t[6]); t[8] = cmulf(t[7], t[6]);
#pragma unroll
  for (int i = 0; i < 9; ++i) {
    u32 hr = (u32)__half_as_ushort(__float2half_rn(t[i].x));
    u32 hi = (u32)__half_as_ushort(__float2half_rn(t[i].y));
    twr[i] = hr | (hr << 16);
    twi[i] = hi | (hi << 16);
  }
}

// Fused 2D FFT per channel plane (verified R8 config): 576 blocks x 1024 thr
// (16 waves), one __syncthreads, 8 FFTs in flight per wave, 129-row LDS.
// 2-blocks/CU restructures (R9/R10/R11) all lost: reg-retention spills,
// plane-split duplicates row work. This 1-block/133KB form is the optimum.
__global__ __launch_bounds__(1024, 4) void fft2_fused(const float* __restrict__ a,
                                                      const float* __restrict__ p,
                                                      const float* __restrict__ n,
                                                      unsigned* __restrict__ outbase,
                                                      float* __restrict__ acc) {
  __shared__ u32 S[129 * SST_];   // 132612 B: [k2][col], packed half2

  int tid = threadIdx.x;
  int wv = tid >> 6;
  int r = tid & 63;
  int tensor = blockIdx.x / 192;
  int plane = blockIdx.x % 192;
  const float* in = (tensor == 0 ? a : (tensor == 1 ? p : n)) + (size_t)plane * 65536;
  unsigned* outp = outbase + (size_t)tensor * TELEMS_ + (size_t)plane * SIMG_;

  if (blockIdx.x == 0 && tid < 192) acc[tid] = 0.0f;   // replaces zero_acc

  u32 twr[9], twi[9];
  tw_init_h(twr, twi, r);
  int m = ((r & 3) << 4) | (((r >> 2) & 3) << 2) | (r >> 4);
  int mp = (64 - m) & 63;
  int rp = ((mp >> 4) & 3) | (((mp >> 2) & 3) << 2) | ((mp & 3) << 4);

  // ---- Row pass: 128 packed-real FFTs (rows 2q,2q+1), 8 per wave ---------
  {
    u32 u[8][4];
#pragma unroll
    for (int f = 0; f < 8; ++f) {
      int q = wv + 16 * f;                    // [0,128)
      const float* rw = in + (size_t)(2 * q) * 256;
#pragma unroll
      for (int j = 0; j < 4; ++j)
        u[f][j] = f2u(make_float2(rw[r + 64 * j], rw[256 + r + 64 * j]));
    }
    fft256h<8>(u, r, twr, twi);
#pragma unroll
    for (int f = 0; f < 8; ++f) {
      int q = wv + 16 * f;
      u32 m0 = (u32)__shfl((int)u[f][0], rp, 64);
      u32 m2 = (u32)__shfl((int)u[f][2], rp, 64);
      u32 m3 = (u32)__shfl((int)u[f][3], rp, 64);
      u32 Zk0 = u[f][0];
      u32 Zk1 = u[f][1];
      u32 Zm0 = (m == 0) ? m0 : m3;
      u32 Zm1 = (m == 0) ? m3 : m2;
      // Aa = 0.5*{Zk.x+Zm.x, Zk.y-Zm.y}; Ab = 0.5*{Zk.y+Zm.y, Zm.x-Zk.x}
      u32 Aa = h2mul(HALF2C_, h2add(Zk0, Zm0 ^ NEG_HI_));
      u32 Ab = h2mul(HALF2C_, h2add(rot16(Zm0), rot16(Zk0) ^ NEG_HI_));
      u32 Ba = h2mul(HALF2C_, h2add(Zk1, Zm1 ^ NEG_HI_));
      u32 Bb = h2mul(HALF2C_, h2add(rot16(Zm1), rot16(Zk1) ^ NEG_HI_));
      S[m * SST_ + 2 * q]            = Aa;
      S[m * SST_ + 2 * q + 1]        = Ab;
      S[(64 + m) * SST_ + 2 * q]     = Ba;
      S[(64 + m) * SST_ + 2 * q + 1] = Bb;
      if (r == 0) {  // Nyquist row k2=128 (slot 2, self-mirror): {Z.x,0},{Z.y,0}
        S[128 * SST_ + 2 * q]     = u[f][2] & 0xFFFFu;
        S[128 * SST_ + 2 * q + 1] = u[f][2] >> 16;
      }
    }
  }

  __syncthreads();                      // the ONE block barrier

  // ---- Column pass: FFT S rows (8 per wave), direct global write ---------
  {
    u32 u[8][4];
#pragma unroll
    for (int f = 0; f < 8; ++f) {
      const u32* row = S + (size_t)(wv + 16 * f) * SST_;
#pragma unroll
      for (int j = 0; j < 4; ++j) u[f][j] = row[r + 64 * j];
    }
    fft256h<8>(u, r, twr, twi);
    // physical pos 4r+s holds freq 64s+m -- fixed within-row permutation, ok
#pragma unroll
    for (int f = 0; f < 8; ++f) {
      int c = wv + 16 * f;
      *(uint4*)(outp + (size_t)c * 256 + 4 * r) =
          make_uint4(u[f][0], u[f][1], u[f][2], u[f][3]);
    }
  }
  if (wv == 0) {                        // row 128
    u32 u1[1][4];
    const u32* srow = S + 128 * SST_;
#pragma unroll
    for (int j = 0; j < 4; ++j) u1[0][j] = srow[r + 64 * j];
    fft256h<1>(u1, r, twr, twi);
    *(uint4*)(outp + (size_t)128 * 256 + 4 * r) =
        make_uint4(u1[0][0], u1[0][1], u1[0][2], u1[0][3]);
  }
  if (wv >= 13) {                       // zero pad rows 129..131
    int c = 129 + (wv - 13);
    *(uint4*)(outp + (size_t)c * 256 + 4 * r) = make_uint4(0, 0, 0, 0);
  }
}

__device__ __forceinline__ float cab2(float2 v) { return v.x * v.x + v.y * v.y; }
// fast 1-instr transcendentals (v_sqrt_f32 / v_rcp_f32, ~1 ulp; tolerance 2e-2)
__device__ __forceinline__ float fsqrt_(float x) { return __builtin_amdgcn_sqrtf(x); }
__device__ __forceinline__ float frcp_(float x) { return __builtin_amdgcn_rcpf(x); }

// -------- Fused normalize + triplet distance, uint2 per thread -------------
// 2 half2 per thread (was 4): data regs 48->24, VGPR ~55 -> 8 waves/SIMD,
// 2x thread population for latency hiding at identical traffic/arithmetic.
__global__ __launch_bounds__(256) void dist_kernel(const unsigned* __restrict__ af,
                                                   const unsigned* __restrict__ pf,
                                                   const unsigned* __restrict__ nf,
                                                   const int* __restrict__ neg,
                                                   float* __restrict__ acc) {
  int b = blockIdx.y;
  int j = (neg[1] == 0) ? (int)((const long long*)neg)[b * 2 + 1] : neg[b * 2 + 1];
  size_t ab = (size_t)b * TIMG_;
  size_t jb = (size_t)j * TIMG_;
  int t2 = blockIdx.x * 256 + threadIdx.x;   // [0, 16896)
  int flat0 = t2 * 2;                        // 2 consecutive elems, same k2 row
  int k2 = flat0 >> 8;
  float w = (k2 == 0 || k2 >= 128) ? 1.0f : 2.0f;

  unsigned A[3][2], P[3][2], N[3][2], M[3][2];
#pragma unroll
  for (int ch = 0; ch < 3; ++ch) {
    uint2 t;
    t = *(const uint2*)(af + ab + ch * SIMG_ + flat0); A[ch][0]=t.x; A[ch][1]=t.y;
    t = *(const uint2*)(pf + ab + ch * SIMG_ + flat0); P[ch][0]=t.x; P[ch][1]=t.y;
    t = *(const uint2*)(nf + ab + ch * SIMG_ + flat0); N[ch][0]=t.x; N[ch][1]=t.y;
    t = *(const uint2*)(nf + jb + ch * SIMG_ + flat0); M[ch][0]=t.x; M[ch][1]=t.y;
  }
  float s_ap = 0.0f, s_a0 = 0.0f, s_a1 = 0.0f;
#pragma unroll
  for (int e = 0; e < 2; ++e) {
    float2 a0 = u2f(A[0][e]), a1 = u2f(A[1][e]), a2 = u2f(A[2][e]);
    float2 p0 = u2f(P[0][e]), p1 = u2f(P[1][e]), p2 = u2f(P[2][e]);
    float2 n0 = u2f(N[0][e]), n1 = u2f(N[1][e]), n2 = u2f(N[2][e]);
    float2 m0 = u2f(M[0][e]), m1 = u2f(M[1][e]), m2 = u2f(M[2][e]);
    float sa = 0.01f * frcp_(fsqrt_(cab2(a0) + cab2(a1) + cab2(a2)) + 1e-8f);
    float sp = 0.01f * frcp_(fsqrt_(cab2(p0) + cab2(p1) + cab2(p2)) + 1e-8f);
    float sn = 0.01f * frcp_(fsqrt_(cab2(n0) + cab2(n1) + cab2(n2)) + 1e-8f);
    float sm = 0.01f * frcp_(fsqrt_(cab2(m0) + cab2(m1) + cab2(m2)) + 1e-8f);
    float dx, dy;
    dx = a0.x * sa - p0.x * sp; dy = a0.y * sa - p0.y * sp; s_ap += fsqrt_(dx * dx + dy * dy);
    dx = a1.x * sa - p1.x * sp; dy = a1.y * sa - p1.y * sp; s_ap += fsqrt_(dx * dx + dy * dy);
    dx = a2.x * sa - p2.x * sp; dy = a2.y * sa - p2.y * sp; s_ap += fsqrt_(dx * dx + dy * dy);
    dx = a0.x * sa - n0.x * sn; dy = a0.y * sa - n0.y * sn; s_a0 += fsqrt_(dx * dx + dy * dy);
    dx = a1.x * sa - n1.x * sn; dy = a1.y * sa - n1.y * sn; s_a0 += fsqrt_(dx * dx + dy * dy);
    dx = a2.x * sa - n2.x * sn; dy = a2.y * sa - n2.y * sn; s_a0 += fsqrt_(dx * dx + dy * dy);
    dx = a0.x * sa - m0.x * sm; dy = a0.y * sa - m0.y * sm; s_a1 += fsqrt_(dx * dx + dy * dy);
    dx = a1.x * sa - m1.x * sm; dy = a1.y * sa - m1.y * sm; s_a1 += fsqrt_(dx * dx + dy * dy);
    dx = a2.x * sa - m2.x * sm; dy = a2.y * sa - m2.y * sm; s_a1 += fsqrt_(dx * dx + dy * dy);
  }
  s_ap *= w; s_a0 *= w; s_a1 *= w;
#pragma unroll
  for (int off = 32; off > 0; off >>= 1) {
    s_ap += __shfl_down(s_ap, off);
    s_a0 += __shfl_down(s_a0, off);
    s_a1 += __shfl_down(s_a1, off);
  }
  __shared__ float red[3][4];
  int lane = threadIdx.x & 63, wid = threadIdx.x >> 6;
  if (lane == 0) { red[0][wid] = s_ap; red[1][wid] = s_a0; red[2][wid] = s_a1; }
  __syncthreads();
  if (threadIdx.x == 0) {
    atomicAdd(&acc[b * 3 + 0], red[0][0] + red[0][1] + red[0][2] + red[0][3]);
    atomicAdd(&acc[b * 3 + 1], red[1][0] + red[1][1] + red[1][2] + red[1][3]);
    atomicAdd(&acc[b * 3 + 2], red[2][0] + red[2][1] + red[2][2] + red[2][3]);
  }
}

__global__ void final_kernel(const float* __restrict__ acc, float* __restrict__ out) {
  int b = threadIdx.x;  // 64 threads
  const float inv = 1.0f / 196608.0f;  // C*H*W (full grid)
  float dap = acc[b * 3 + 0] * inv;
  float da0 = acc[b * 3 + 1] * inv;
  float da1 = acc[b * 3 + 2] * inv;
  float term = dap / (da0 + 1e-7f) + dap / (da1 + 1e-7f);
#pragma unroll
  for (int off = 32; off > 0; off >>= 1) term += __shfl_down(term, off);
  if (b == 0) out[0] = term * (1.0f / 128.0f);  // / (K*B)
}

extern "C" void kernel_launch(void* const* d_in, const int* in_sizes, int n_in,
                              void* d_out, int out_size, void* d_ws, size_t ws_size,
                              hipStream_t stream) {
  const float* a = (const float*)d_in[0];
  const float* p = (const float*)d_in[1];
  const float* n = (const float*)d_in[2];
  const int* neg = (const int*)d_in[3];
  float* out = (float*)d_out;

  unsigned* base = (unsigned*)d_ws;             // af | pf | nf, TELEMS_ each
  float* acc = (float*)(base + 3 * TELEMS_);    // ~74.3 MB + 768 B total

  fft2_fused<<<576, 1024, 0, stream>>>(a, p, n, base, acc);
  dist_kernel<<<dim3(66, 64), 256, 0, stream>>>(base, base + TELEMS_,
                                                base + 2 * TELEMS_, neg, acc);
  final_kernel<<<1, 64, 0, stream>>>(acc, out);
}

// Round 13
// 227.638 us; speedup vs baseline: 1.1180x; 1.1180x over previous
//
#include <hip/hip_runtime.h>
#include <hip/hip_fp16.h>

// Problem constants
#define B_ 64
#define SW_ 132                 // stored k2 rows: [0,128] real + [129,131] zero pad
#define SIMG_ (256 * SW_)       // 33792 packed half2 per channel plane
#define TIMG_ (3 * SIMG_)       // per batch item per tensor
#define TELEMS_ ((size_t)B_ * TIMG_)
#define SST_ 257                // S row stride (odd -> conflict-free strided access)

typedef unsigned u32;

// ---- packed half2 primitives (compile to v_pk_*_f16 / v_alignbit) --------
__device__ __forceinline__ u32 h2add(u32 a, u32 b) {
  __half2 r = __hadd2(__builtin_bit_cast(__half2, a), __builtin_bit_cast(__half2, b));
  return __builtin_bit_cast(u32, r);
}
__device__ __forceinline__ u32 h2sub(u32 a, u32 b) {
  __half2 r = __hsub2(__builtin_bit_cast(__half2, a), __builtin_bit_cast(__half2, b));
  return __builtin_bit_cast(u32, r);
}
__device__ __forceinline__ u32 h2mul(u32 a, u32 b) {
  __half2 r = __hmul2(__builtin_bit_cast(__half2, a), __builtin_bit_cast(__half2, b));
  return __builtin_bit_cast(u32, r);
}
__device__ __forceinline__ u32 h2fma(u32 a, u32 b, u32 c) {
  __half2 r = __hfma2(__builtin_bit_cast(__half2, a), __builtin_bit_cast(__half2, b),
                      __builtin_bit_cast(__half2, c));
  return __builtin_bit_cast(u32, r);
}
__device__ __forceinline__ u32 rot16(u32 u) { return (u >> 16) | (u << 16); }
#define NEG_HI_ 0x80000000u     // flip sign of .y (im)
#define NEG_LO_ 0x00008000u     // flip sign of .x (re)
#define HALF2C_ 0x38003800u     // {0.5h, 0.5h}

// complex mul by twiddle given duplicated halves tr={c,c}, ti={s,s}:
// {x.re*c - x.im*s, x.im*c + x.re*s}
__device__ __forceinline__ u32 cmulh(u32 x, u32 tr, u32 ti) {
  u32 m = h2mul(rot16(x), ti);          // {x.im*s, x.re*s}
  return h2fma(x, tr, m ^ NEG_LO_);     // {x.re*c - x.im*s, x.im*c + x.re*s}
}

__device__ __forceinline__ u32 f2u(float2 v) {
  __half2 h = __float22half2_rn(v);
  return __builtin_bit_cast(u32, h);
}
__device__ __forceinline__ float2 u2f(u32 u) {
  return __half22float2(__builtin_bit_cast(__half2, u));
}
__device__ __forceinline__ float2 cmulf(float2 a, float2 b) {
  return make_float2(a.x * b.x - a.y * b.y, a.x * b.y + a.y * b.x);
}

// radix-4 DIF butterfly on 4 half2 slots (intra-lane), optional twiddles
__device__ __forceinline__ void bfly4h(u32 x[4], const u32* twr, const u32* twi, bool tw) {
  u32 a = h2add(x[0], x[2]);
  u32 b = h2sub(x[0], x[2]);
  u32 c = h2add(x[1], x[3]);
  u32 d = h2sub(x[1], x[3]);
  u32 e = rot16(d);                     // {d.y, d.x}
  u32 y1 = h2add(b, e ^ NEG_HI_);       // b - i d = {b.x + d.y, b.y - d.x}
  u32 y2 = h2sub(a, c);
  u32 y3 = h2add(b, e ^ NEG_LO_);       // b + i d = {b.x - d.y, b.y + d.x}
  x[0] = h2add(a, c);
  if (tw) { y1 = cmulh(y1, twr[0], twi[0]); y2 = cmulh(y2, twr[1], twi[1]);
            y3 = cmulh(y3, twr[2], twi[2]); }
  x[1] = y1; x[2] = y2; x[3] = y3;
}

// ---- gfx950-native lane exchanges ----------------------------------------
__device__ __forceinline__ void swap16(u32& A, u32& B) {
  asm("v_permlane16_swap_b32 %0, %1" : "+v"(A), "+v"(B));
}
__device__ __forceinline__ void swap32(u32& A, u32& B) {
  asm("v_permlane32_swap_b32 %0, %1" : "+v"(A), "+v"(B));
}
template <int BIT>
__device__ __forceinline__ void xsel(u32& A, u32& B, int r) {
  bool hi = (r >> BIT) & 1;
  int send = hi ? (int)A : (int)B;
  int got;
  if constexpr (BIT == 0)
    got = __builtin_amdgcn_update_dpp(0, send, 0xB1, 0xF, 0xF, false);
  else if constexpr (BIT == 1)
    got = __builtin_amdgcn_update_dpp(0, send, 0x4E, 0xF, 0xF, false);
  else if constexpr (BIT == 2)
    got = __builtin_amdgcn_ds_swizzle(send, 0x101F);
  else
    got = __builtin_amdgcn_ds_swizzle(send, 0x201F);
  if (hi) A = (u32)got; else B = (u32)got;
}
__device__ __forceinline__ void xdig45(u32 u[4]) {
  swap16(u[0], u[1]);
  swap16(u[2], u[3]);
  swap32(u[0], u[2]);
  swap32(u[1], u[3]);
}
template <int BIT>
__device__ __forceinline__ void xdig(u32 u[4], int r) {
  xsel<BIT>(u[0], u[1], r);
  xsel<BIT>(u[2], u[3], r);
  xsel<BIT + 1>(u[0], u[2], r);
  xsel<BIT + 1>(u[1], u[3], r);
}

// NF independent 256-pt radix-4 DIF FFTs per wave, fully half2-resident.
// Input u[f][4] half2 with slot = d3 (element e = r + 64*slot). Output packed:
// lane r slot s holds X[k], k = 64*s + 16*(r&3) + 4*((r>>2)&3) + (r>>4).
template <int NF>
__device__ __forceinline__ void fft256h(u32 (&u)[NF][4], int r,
                                        const u32 twr[9], const u32 twi[9]) {
#pragma unroll
  for (int f = 0; f < NF; ++f) bfly4h(u[f], twr + 0, twi + 0, true);
#pragma unroll
  for (int f = 0; f < NF; ++f) xdig45(u[f]);                    // d3 <-> d2
#pragma unroll
  for (int f = 0; f < NF; ++f) bfly4h(u[f], twr + 3, twi + 3, true);
#pragma unroll
  for (int f = 0; f < NF; ++f) xdig<2>(u[f], r);                // d2 <-> d1
#pragma unroll
  for (int f = 0; f < NF; ++f) bfly4h(u[f], twr + 6, twi + 6, true);
#pragma unroll
  for (int f = 0; f < NF; ++f) xdig<0>(u[f], r);                // d1 <-> d0
#pragma unroll
  for (int f = 0; f < NF; ++f) bfly4h(u[f], twr, twi, false);
}

// per-lane duplicated-half2 twiddles (function of lane id only)
__device__ __forceinline__ void tw_init_h(u32 twr[9], u32 twi[9], int r) {
  float2 t[9];
  float s, c;
  __sincosf(-6.283185307179586f * (float)r / 256.0f, &s, &c);
  t[0] = make_float2(c, s); t[1] = cmulf(t[0], t[0]); t[2] = cmulf(t[1], t[0]);
  __sincosf(-6.283185307179586f * (float)(r & 15) / 64.0f, &s, &c);
  t[3] = make_float2(c, s); t[4] = cmulf(t[3], t[3]); t[5] = cmulf(t[4], t[3]);
  __sincosf(-6.283185307179586f * (float)(r & 3) / 16.0f, &s, &c);
  t[6] = make_float2(c, s); t[7] = cmulf(t[6], t[6]); t[8] = cmulf(t[7], t[6]);
#pragma unroll
  for (int i = 0; i < 9; ++i) {
    u32 hr = (u32)__half_as_ushort(__float2half_rn(t[i].x));
    u32 hi = (u32)__half_as_ushort(__float2half_rn(t[i].y));
    twr[i] = hr | (hr << 16);
    twi[i] = hi | (hi << 16);
  }
}

// Fused 2D FFT per channel plane (verified R8 config): 576 blocks x 1024 thr
// (16 waves), one __syncthreads, 8 FFTs in flight per wave, 129-row LDS.
// 2-blocks/CU restructures (R9/R10/R11) all lost: reg-retention spills,
// plane-split duplicates row work. This 1-block/133KB form is the optimum.
__global__ __launch_bounds__(1024, 4) void fft2_fused(const float* __restrict__ a,
                                                      const float* __restrict__ p,
                                                      const float* __restrict__ n,
                                                      unsigned* __restrict__ outbase,
                                                      float* __restrict__ acc) {
  __shared__ u32 S[129 * SST_];   // 132612 B: [k2][col], packed half2

  int tid = threadIdx.x;
  int wv = tid >> 6;
  int r = tid & 63;
  int tensor = blockIdx.x / 192;
  int plane = blockIdx.x % 192;
  const float* in = (tensor == 0 ? a : (tensor == 1 ? p : n)) + (size_t)plane * 65536;
  unsigned* outp = outbase + (size_t)tensor * TELEMS_ + (size_t)plane * SIMG_;

  if (blockIdx.x == 0 && tid < 192) acc[tid] = 0.0f;   // replaces zero_acc

  u32 twr[9], twi[9];
  tw_init_h(twr, twi, r);
  int m = ((r & 3) << 4) | (((r >> 2) & 3) << 2) | (r >> 4);
  int mp = (64 - m) & 63;
  int rp = ((mp >> 4) & 3) | (((mp >> 2) & 3) << 2) | ((mp & 3) << 4);

  // ---- Row pass: 128 packed-real FFTs (rows 2q,2q+1), 8 per wave ---------
  {
    u32 u[8][4];
#pragma unroll
    for (int f = 0; f < 8; ++f) {
      int q = wv + 16 * f;                    // [0,128)
      const float* rw = in + (size_t)(2 * q) * 256;
#pragma unroll
      for (int j = 0; j < 4; ++j)
        u[f][j] = f2u(make_float2(rw[r + 64 * j], rw[256 + r + 64 * j]));
    }
    fft256h<8>(u, r, twr, twi);
#pragma unroll
    for (int f = 0; f < 8; ++f) {
      int q = wv + 16 * f;
      u32 m0 = (u32)__shfl((int)u[f][0], rp, 64);
      u32 m2 = (u32)__shfl((int)u[f][2], rp, 64);
      u32 m3 = (u32)__shfl((int)u[f][3], rp, 64);
      u32 Zk0 = u[f][0];
      u32 Zk1 = u[f][1];
      u32 Zm0 = (m == 0) ? m0 : m3;
      u32 Zm1 = (m == 0) ? m3 : m2;
      // Aa = 0.5*{Zk.x+Zm.x, Zk.y-Zm.y}; Ab = 0.5*{Zk.y+Zm.y, Zm.x-Zk.x}
      u32 Aa = h2mul(HALF2C_, h2add(Zk0, Zm0 ^ NEG_HI_));
      u32 Ab = h2mul(HALF2C_, h2add(rot16(Zm0), rot16(Zk0) ^ NEG_HI_));
      u32 Ba = h2mul(HALF2C_, h2add(Zk1, Zm1 ^ NEG_HI_));
      u32 Bb = h2mul(HALF2C_, h2add(rot16(Zm1), rot16(Zk1) ^ NEG_HI_));
      S[m * SST_ + 2 * q]            = Aa;
      S[m * SST_ + 2 * q + 1]        = Ab;
      S[(64 + m) * SST_ + 2 * q]     = Ba;
      S[(64 + m) * SST_ + 2 * q + 1] = Bb;
      if (r == 0) {  // Nyquist row k2=128 (slot 2, self-mirror): {Z.x,0},{Z.y,0}
        S[128 * SST_ + 2 * q]     = u[f][2] & 0xFFFFu;
        S[128 * SST_ + 2 * q + 1] = u[f][2] >> 16;
      }
    }
  }

  __syncthreads();                      // the ONE block barrier

  // ---- Column pass: FFT S rows (8 per wave), direct global write ---------
  {
    u32 u[8][4];
#pragma unroll
    for (int f = 0; f < 8; ++f) {
      const u32* row = S + (size_t)(wv + 16 * f) * SST_;
#pragma unroll
      for (int j = 0; j < 4; ++j) u[f][j] = row[r + 64 * j];
    }
    fft256h<8>(u, r, twr, twi);
    // physical pos 4r+s holds freq 64s+m -- fixed within-row permutation, ok
#pragma unroll
    for (int f = 0; f < 8; ++f) {
      int c = wv + 16 * f;
      *(uint4*)(outp + (size_t)c * 256 + 4 * r) =
          make_uint4(u[f][0], u[f][1], u[f][2], u[f][3]);
    }
  }
  if (wv == 0) {                        // row 128
    u32 u1[1][4];
    const u32* srow = S + 128 * SST_;
#pragma unroll
    for (int j = 0; j < 4; ++j) u1[0][j] = srow[r + 64 * j];
    fft256h<1>(u1, r, twr, twi);
    *(uint4*)(outp + (size_t)128 * 256 + 4 * r) =
        make_uint4(u1[0][0], u1[0][1], u1[0][2], u1[0][3]);
  }
  if (wv >= 13) {                       // zero pad rows 129..131
    int c = 129 + (wv - 13);
    *(uint4*)(outp + (size_t)c * 256 + 4 * r) = make_uint4(0, 0, 0, 0);
  }
}

__device__ __forceinline__ float cab2(float2 v) { return v.x * v.x + v.y * v.y; }
// fast 1-instr transcendentals (v_sqrt_f32 / v_rcp_f32, ~1 ulp; tolerance 2e-2)
__device__ __forceinline__ float fsqrt_(float x) { return __builtin_amdgcn_sqrtf(x); }
__device__ __forceinline__ float frcp_(float x) { return __builtin_amdgcn_rcpf(x); }

// -------- Fused normalize + triplet distance, 8 elems (2x uint4) / thread --
// R12 lesson: 2 elems/thread (+2x threads) cost +24 us -> per-thread fixed
// work (12 stream addresses, reduction, atomics) dominates dist. Go the
// other way: 8 elems/thread halves thread count vs R8; two groups of 12
// uint4 loads keep register pressure near R8's while the compiler pipelines
// group-1 loads under group-0 compute. Same bytes, same math, same weights.
__global__ __launch_bounds__(256) void dist_kernel(const unsigned* __restrict__ af,
                                                   const unsigned* __restrict__ pf,
                                                   const unsigned* __restrict__ nf,
                                                   const int* __restrict__ neg,
                                                   float* __restrict__ acc) {
  int b = blockIdx.y;
  int j = (neg[1] == 0) ? (int)((const long long*)neg)[b * 2 + 1] : neg[b * 2 + 1];
  size_t ab = (size_t)b * TIMG_;
  size_t jb = (size_t)j * TIMG_;
  int t8 = blockIdx.x * 256 + threadIdx.x;   // [0, 4352); active < 4224
  bool act = t8 < 4224;
  int flat0 = t8 * 8;                        // 8 consecutive elems, same k2 row
  int k2 = flat0 >> 8;
  float w = (k2 == 0 || k2 >= 128) ? 1.0f : 2.0f;

  float s_ap = 0.0f, s_a0 = 0.0f, s_a1 = 0.0f;
  if (act) {
#pragma unroll
    for (int g = 0; g < 2; ++g) {
      int off = flat0 + 4 * g;
      unsigned A[3][4], P[3][4], N[3][4], M[3][4];
#pragma unroll
      for (int ch = 0; ch < 3; ++ch) {
        uint4 t;
        t = *(const uint4*)(af + ab + ch * SIMG_ + off); A[ch][0]=t.x; A[ch][1]=t.y; A[ch][2]=t.z; A[ch][3]=t.w;
        t = *(const uint4*)(pf + ab + ch * SIMG_ + off); P[ch][0]=t.x; P[ch][1]=t.y; P[ch][2]=t.z; P[ch][3]=t.w;
        t = *(const uint4*)(nf + ab + ch * SIMG_ + off); N[ch][0]=t.x; N[ch][1]=t.y; N[ch][2]=t.z; N[ch][3]=t.w;
        t = *(const uint4*)(nf + jb + ch * SIMG_ + off); M[ch][0]=t.x; M[ch][1]=t.y; M[ch][2]=t.z; M[ch][3]=t.w;
      }
#pragma unroll
      for (int e = 0; e < 4; ++e) {
        float2 a0 = u2f(A[0][e]), a1 = u2f(A[1][e]), a2 = u2f(A[2][e]);
        float2 p0 = u2f(P[0][e]), p1 = u2f(P[1][e]), p2 = u2f(P[2][e]);
        float2 n0 = u2f(N[0][e]), n1 = u2f(N[1][e]), n2 = u2f(N[2][e]);
        float2 m0 = u2f(M[0][e]), m1 = u2f(M[1][e]), m2 = u2f(M[2][e]);
        float sa = 0.01f * frcp_(fsqrt_(cab2(a0) + cab2(a1) + cab2(a2)) + 1e-8f);
        float sp = 0.01f * frcp_(fsqrt_(cab2(p0) + cab2(p1) + cab2(p2)) + 1e-8f);
        float sn = 0.01f * frcp_(fsqrt_(cab2(n0) + cab2(n1) + cab2(n2)) + 1e-8f);
        float sm = 0.01f * frcp_(fsqrt_(cab2(m0) + cab2(m1) + cab2(m2)) + 1e-8f);
        float dx, dy;
        dx = a0.x * sa - p0.x * sp; dy = a0.y * sa - p0.y * sp; s_ap += fsqrt_(dx * dx + dy * dy);
        dx = a1.x * sa - p1.x * sp; dy = a1.y * sa - p1.y * sp; s_ap += fsqrt_(dx * dx + dy * dy);
        dx = a2.x * sa - p2.x * sp; dy = a2.y * sa - p2.y * sp; s_ap += fsqrt_(dx * dx + dy * dy);
        dx = a0.x * sa - n0.x * sn; dy = a0.y * sa - n0.y * sn; s_a0 += fsqrt_(dx * dx + dy * dy);
        dx = a1.x * sa - n1.x * sn; dy = a1.y * sa - n1.y * sn; s_a0 += fsqrt_(dx * dx + dy * dy);
        dx = a2.x * sa - n2.x * sn; dy = a2.y * sa - n2.y * sn; s_a0 += fsqrt_(dx * dx + dy * dy);
        dx = a0.x * sa - m0.x * sm; dy = a0.y * sa - m0.y * sm; s_a1 += fsqrt_(dx * dx + dy * dy);
        dx = a1.x * sa - m1.x * sm; dy = a1.y * sa - m1.y * sm; s_a1 += fsqrt_(dx * dx + dy * dy);
        dx = a2.x * sa - m2.x * sm; dy = a2.y * sa - m2.y * sm; s_a1 += fsqrt_(dx * dx + dy * dy);
      }
    }
  }
  s_ap *= w; s_a0 *= w; s_a1 *= w;
#pragma unroll
  for (int off = 32; off > 0; off >>= 1) {
    s_ap += __shfl_down(s_ap, off);
    s_a0 += __shfl_down(s_a0, off);
    s_a1 += __shfl_down(s_a1, off);
  }
  __shared__ float red[3][4];
  int lane = threadIdx.x & 63, wid = threadIdx.x >> 6;
  if (lane == 0) { red[0][wid] = s_ap; red[1][wid] = s_a0; red[2][wid] = s_a1; }
  __syncthreads();
  if (threadIdx.x == 0) {
    atomicAdd(&acc[b * 3 + 0], red[0][0] + red[0][1] + red[0][2] + red[0][3]);
    atomicAdd(&acc[b * 3 + 1], red[1][0] + red[1][1] + red[1][2] + red[1][3]);
    atomicAdd(&acc[b * 3 + 2], red[2][0] + red[2][1] + red[2][2] + red[2][3]);
  }
}

__global__ void final_kernel(const float* __restrict__ acc, float* __restrict__ out) {
  int b = threadIdx.x;  // 64 threads
  const float inv = 1.0f / 196608.0f;  // C*H*W (full grid)
  float dap = acc[b * 3 + 0] * inv;
  float da0 = acc[b * 3 + 1] * inv;
  float da1 = acc[b * 3 + 2] * inv;
  float term = dap / (da0 + 1e-7f) + dap / (da1 + 1e-7f);
#pragma unroll
  for (int off = 32; off > 0; off >>= 1) term += __shfl_down(term, off);
  if (b == 0) out[0] = term * (1.0f / 128.0f);  // / (K*B)
}

extern "C" void kernel_launch(void* const* d_in, const int* in_sizes, int n_in,
                              void* d_out, int out_size, void* d_ws, size_t ws_size,
                              hipStream_t stream) {
  const float* a = (const float*)d_in[0];
  const float* p = (const float*)d_in[1];
  const float* n = (const float*)d_in[2];
  const int* neg = (const int*)d_in[3];
  float* out = (float*)d_out;

  unsigned* base = (unsigned*)d_ws;             // af | pf | nf, TELEMS_ each
  float* acc = (float*)(base + 3 * TELEMS_);    // ~74.3 MB + 768 B total

  fft2_fused<<<576, 1024, 0, stream>>>(a, p, n, base, acc);
  dist_kernel<<<dim3(17, 64), 256, 0, stream>>>(base, base + TELEMS_,
                                                base + 2 * TELEMS_, neg, acc);
  final_kernel<<<1, 64, 0, stream>>>(acc, out);
}